// Round 2
// baseline (1493.944 us; speedup 1.0000x reference)
//
#include <hip/hip_runtime.h>
#include <stdint.h>

typedef __bf16 bf16;
typedef __bf16 bf16x8 __attribute__((ext_vector_type(8)));
typedef float f32x4 __attribute__((ext_vector_type(4)));

#define NN 30000
#define NE 300000
#define NG 128
#define DD 128

// ---------------------------------------------------------------------------
// f32-accurate GEMM via 3-term bf16 split: a*b ~= ah*bh + ah*bl + al*bh.
// MODE 0: A = plain f32 [M x K] streamed.
// MODE 1: A streamed; epilogue adds s0[i0[m]*256+n] + s1[i1[m]*256+n]
//         (edge L1: A=eattr, s0=Pr (incl. u-term), s1=Pc, i0=row, i1=col).
// MODE 2: A = [s0[gm] | s1[gm]] concat by K-half (DD each); epilogue adds
//         s2[i2[m]*256+n]  (node L1: s0=nodes, s1=agg, s2=Pun, i2=batch;
//         also Pr build: K=128, s0=nodes, s2=Pu, i2=batch).
// ---------------------------------------------------------------------------
template <int MODE>
__global__ __launch_bounds__(512) void gemm_wide(
    const float* __restrict__ A, const bf16* __restrict__ Bh,
    const bf16* __restrict__ Bl, const float* __restrict__ bias,
    float* __restrict__ C, int M, int K, int do_relu,
    const float* __restrict__ s0, const float* __restrict__ s1,
    const float* __restrict__ s2, const int* __restrict__ i0,
    const int* __restrict__ i1, const int* __restrict__ i2) {
  __shared__ bf16 Ash[128 * 32];
  __shared__ bf16 Asl[128 * 32];
  __shared__ bf16 Bsh[256 * 32];
  __shared__ bf16 Bsl[256 * 32];
  const int tid = threadIdx.x;
  const int w = tid >> 6, lane = tid & 63;
  const int wm = w >> 2, wn = w & 3;  // 2 x 4 waves over 128 x 256
  const int m0 = blockIdx.x * 128;
  const int ar = tid >> 2;        // 0..127: A row / B row pair
  const int k8 = (tid & 3) * 8;   // 0,8,16,24 within 32-wide k-slab

  int gm = m0 + ar;
  if (gm > M - 1) gm = M - 1;  // clamp partial tile; stores guarded below

  f32x4 acc[4][4];
#pragma unroll
  for (int a = 0; a < 4; ++a)
#pragma unroll
    for (int b = 0; b < 4; ++b) acc[a][b] = {0.f, 0.f, 0.f, 0.f};

  for (int k0 = 0; k0 < K; k0 += 32) {
    const float* ga;
    if (MODE == 2) {
      int kk = k0 + k8;
      ga = (kk < DD) ? (s0 + (size_t)gm * DD + kk)
                     : (s1 + (size_t)gm * DD + (kk - DD));
    } else {
      ga = A + (size_t)gm * K + k0 + k8;
    }
    f32x4 a0 = *(const f32x4*)ga;
    f32x4 a1 = *(const f32x4*)(ga + 4);
    bf16x8 vh, vl;
#pragma unroll
    for (int i = 0; i < 4; ++i) {
      float x = a0[i];
      bf16 h = (bf16)x;
      vh[i] = h;
      vl[i] = (bf16)(x - (float)h);
    }
#pragma unroll
    for (int i = 0; i < 4; ++i) {
      float x = a1[i];
      bf16 h = (bf16)x;
      vh[4 + i] = h;
      vl[4 + i] = (bf16)(x - (float)h);
    }
    bf16x8 bh0 = *(const bf16x8*)(Bh + (size_t)ar * K + k0 + k8);
    bf16x8 bl0 = *(const bf16x8*)(Bl + (size_t)ar * K + k0 + k8);
    bf16x8 bh1 = *(const bf16x8*)(Bh + (size_t)(ar + 128) * K + k0 + k8);
    bf16x8 bl1 = *(const bf16x8*)(Bl + (size_t)(ar + 128) * K + k0 + k8);

    __syncthreads();
    *(bf16x8*)&Ash[ar * 32 + k8] = vh;
    *(bf16x8*)&Asl[ar * 32 + k8] = vl;
    *(bf16x8*)&Bsh[ar * 32 + k8] = bh0;
    *(bf16x8*)&Bsl[ar * 32 + k8] = bl0;
    *(bf16x8*)&Bsh[(ar + 128) * 32 + k8] = bh1;
    *(bf16x8*)&Bsl[(ar + 128) * 32 + k8] = bl1;
    __syncthreads();

    const int lr = lane & 15, q8 = (lane >> 4) * 8;
    bf16x8 afh[4], afl[4], bfh[4], bfl[4];
#pragma unroll
    for (int mi = 0; mi < 4; ++mi) {
      afh[mi] = *(const bf16x8*)&Ash[(wm * 64 + mi * 16 + lr) * 32 + q8];
      afl[mi] = *(const bf16x8*)&Asl[(wm * 64 + mi * 16 + lr) * 32 + q8];
    }
#pragma unroll
    for (int ni = 0; ni < 4; ++ni) {
      bfh[ni] = *(const bf16x8*)&Bsh[(wn * 64 + ni * 16 + lr) * 32 + q8];
      bfl[ni] = *(const bf16x8*)&Bsl[(wn * 64 + ni * 16 + lr) * 32 + q8];
    }
#pragma unroll
    for (int mi = 0; mi < 4; ++mi)
#pragma unroll
      for (int ni = 0; ni < 4; ++ni) {
        acc[mi][ni] = __builtin_amdgcn_mfma_f32_16x16x32_bf16(
            afl[mi], bfh[ni], acc[mi][ni], 0, 0, 0);
        acc[mi][ni] = __builtin_amdgcn_mfma_f32_16x16x32_bf16(
            afh[mi], bfl[ni], acc[mi][ni], 0, 0, 0);
        acc[mi][ni] = __builtin_amdgcn_mfma_f32_16x16x32_bf16(
            afh[mi], bfh[ni], acc[mi][ni], 0, 0, 0);
      }
  }

  // C/D layout: col=lane&15, row=(lane>>4)*4+reg  [measured m89/m91]
  const int lr = lane & 15;
  const int rq = (lane >> 4) * 4;
  float bb[4];
#pragma unroll
  for (int ni = 0; ni < 4; ++ni) bb[ni] = bias[wn * 64 + ni * 16 + lr];
#pragma unroll
  for (int mi = 0; mi < 4; ++mi) {
#pragma unroll
    for (int r = 0; r < 4; ++r) {
      int m = m0 + wm * 64 + mi * 16 + rq + r;
      if (m >= M) continue;
      const float* p0 = nullptr;
      const float* p1 = nullptr;
      const float* p2 = nullptr;
      if (MODE == 1) {
        int rv = i0[m], cv = i1[m];
        p0 = s0 + (size_t)rv * 256;
        p1 = s1 + (size_t)cv * 256;
      } else if (MODE == 2) {
        int gv = i2[m];
        p2 = s2 + (size_t)gv * 256;
      }
#pragma unroll
      for (int ni = 0; ni < 4; ++ni) {
        int n = wn * 64 + ni * 16 + lr;
        float v = acc[mi][ni][r] + bb[ni];
        if (MODE == 1) v += p0[n] + p1[n];
        if (MODE == 2) v += p2[n];
        if (do_relu) v = v > 0.f ? v : 0.f;
        C[(size_t)m * 256 + n] = v;
      }
    }
  }
}

// 128x128-tile GEMM, 256 threads, plain f32 A (final N=128 layers).
__global__ __launch_bounds__(256) void gemm128(
    const float* __restrict__ A, const bf16* __restrict__ Bh,
    const bf16* __restrict__ Bl, const float* __restrict__ bias,
    float* __restrict__ C, int M, int N, int K, int do_relu) {
  __shared__ bf16 Ash[128 * 32];
  __shared__ bf16 Asl[128 * 32];
  __shared__ bf16 Bsh[128 * 32];
  __shared__ bf16 Bsl[128 * 32];
  const int tid = threadIdx.x;
  const int w = tid >> 6, lane = tid & 63;
  const int wm = w >> 1, wn = w & 1;
  const int m0 = blockIdx.x * 128, n0 = blockIdx.y * 128;
  const int ar = tid >> 2;
  const int k8 = (tid & 3) * 8;

  int gmA0 = m0 + ar;      if (gmA0 > M - 1) gmA0 = M - 1;
  int gmA1 = m0 + ar + 64; if (gmA1 > M - 1) gmA1 = M - 1;

  f32x4 acc[4][4];
#pragma unroll
  for (int a = 0; a < 4; ++a)
#pragma unroll
    for (int b = 0; b < 4; ++b) acc[a][b] = {0.f, 0.f, 0.f, 0.f};

  for (int k0 = 0; k0 < K; k0 += 32) {
    f32x4 a00 = *(const f32x4*)(A + (size_t)gmA0 * K + k0 + k8);
    f32x4 a01 = *(const f32x4*)(A + (size_t)gmA0 * K + k0 + k8 + 4);
    f32x4 a10 = *(const f32x4*)(A + (size_t)gmA1 * K + k0 + k8);
    f32x4 a11 = *(const f32x4*)(A + (size_t)gmA1 * K + k0 + k8 + 4);
    bf16x8 v0h, v0l, v1h, v1l;
#pragma unroll
    for (int i = 0; i < 4; ++i) {
      float x = a00[i]; bf16 h = (bf16)x; v0h[i] = h; v0l[i] = (bf16)(x - (float)h);
      x = a01[i]; h = (bf16)x; v0h[4 + i] = h; v0l[4 + i] = (bf16)(x - (float)h);
      x = a10[i]; h = (bf16)x; v1h[i] = h; v1l[i] = (bf16)(x - (float)h);
      x = a11[i]; h = (bf16)x; v1h[4 + i] = h; v1l[4 + i] = (bf16)(x - (float)h);
    }
    bf16x8 bh0 = *(const bf16x8*)(Bh + (size_t)(n0 + ar) * K + k0 + k8);
    bf16x8 bl0 = *(const bf16x8*)(Bl + (size_t)(n0 + ar) * K + k0 + k8);
    bf16x8 bh1 = *(const bf16x8*)(Bh + (size_t)(n0 + ar + 64) * K + k0 + k8);
    bf16x8 bl1 = *(const bf16x8*)(Bl + (size_t)(n0 + ar + 64) * K + k0 + k8);

    __syncthreads();
    *(bf16x8*)&Ash[ar * 32 + k8] = v0h;
    *(bf16x8*)&Asl[ar * 32 + k8] = v0l;
    *(bf16x8*)&Ash[(ar + 64) * 32 + k8] = v1h;
    *(bf16x8*)&Asl[(ar + 64) * 32 + k8] = v1l;
    *(bf16x8*)&Bsh[ar * 32 + k8] = bh0;
    *(bf16x8*)&Bsl[ar * 32 + k8] = bl0;
    *(bf16x8*)&Bsh[(ar + 64) * 32 + k8] = bh1;
    *(bf16x8*)&Bsl[(ar + 64) * 32 + k8] = bl1;
    __syncthreads();

    const int lr = lane & 15, q8 = (lane >> 4) * 8;
    bf16x8 afh[4], afl[4], bfh[4], bfl[4];
#pragma unroll
    for (int mi = 0; mi < 4; ++mi) {
      afh[mi] = *(const bf16x8*)&Ash[(wm * 64 + mi * 16 + lr) * 32 + q8];
      afl[mi] = *(const bf16x8*)&Asl[(wm * 64 + mi * 16 + lr) * 32 + q8];
    }
#pragma unroll
    for (int ni = 0; ni < 4; ++ni) {
      bfh[ni] = *(const bf16x8*)&Bsh[(wn * 64 + ni * 16 + lr) * 32 + q8];
      bfl[ni] = *(const bf16x8*)&Bsl[(wn * 64 + ni * 16 + lr) * 32 + q8];
    }
#pragma unroll
    for (int mi = 0; mi < 4; ++mi)
#pragma unroll
      for (int ni = 0; ni < 4; ++ni) {
        acc[mi][ni] = __builtin_amdgcn_mfma_f32_16x16x32_bf16(
            afl[mi], bfh[ni], acc[mi][ni], 0, 0, 0);
        acc[mi][ni] = __builtin_amdgcn_mfma_f32_16x16x32_bf16(
            afh[mi], bfl[ni], acc[mi][ni], 0, 0, 0);
        acc[mi][ni] = __builtin_amdgcn_mfma_f32_16x16x32_bf16(
            afh[mi], bfh[ni], acc[mi][ni], 0, 0, 0);
      }
  }

  const int lr = lane & 15;
  const int rq = (lane >> 4) * 4;
#pragma unroll
  for (int ni = 0; ni < 4; ++ni) {
    int n = n0 + wn * 64 + ni * 16 + lr;
    float bb = bias[n];
#pragma unroll
    for (int mi = 0; mi < 4; ++mi) {
#pragma unroll
      for (int r = 0; r < 4; ++r) {
        int m = m0 + wm * 64 + mi * 16 + rq + r;
        if (m < M) {
          float v = acc[mi][ni][r] + bb;
          if (do_relu) v = v > 0.f ? v : 0.f;
          C[(size_t)m * N + n] = v;
        }
      }
    }
  }
}

__global__ void splitw_k(const float* __restrict__ W, bf16* __restrict__ Wh,
                         bf16* __restrict__ Wl, int K, int N) {
  int i = blockIdx.x * 256 + threadIdx.x;
  if (i < K * N) {
    int k = i / N, n = i % N;
    float x = W[i];
    bf16 h = (bf16)x;
    Wh[(size_t)n * K + k] = h;
    Wl[(size_t)n * K + k] = (bf16)(x - (float)h);
  }
}

// ---------------------------------------------------------------------------
// CSR build over col + per-graph edge counts (batch[row]).
// ---------------------------------------------------------------------------
__global__ __launch_bounds__(256) void csr_cnt_k(
    const int* __restrict__ col, const int* __restrict__ row,
    const int* __restrict__ batch, int* __restrict__ cnt_i,
    float* __restrict__ cnt_ge) {
  __shared__ float hist[NG];
  const int tid = threadIdx.x;
  if (tid < NG) hist[tid] = 0.f;
  __syncthreads();
  for (int e = blockIdx.x * 256 + tid; e < NE; e += gridDim.x * 256) {
    atomicAdd(&cnt_i[col[e]], 1);
    atomicAdd(&hist[batch[row[e]]], 1.f);
  }
  __syncthreads();
  if (tid < NG) atomicAdd(&cnt_ge[tid], hist[tid]);
}

#define SCAN_T 1024
#define SCAN_C 30  // 1024*30 = 30720 >= NN
__global__ __launch_bounds__(1024) void scan_k(const int* __restrict__ cnt_i,
                                               int* __restrict__ eoff,
                                               int* __restrict__ cursor) {
  __shared__ int tot[SCAN_T];
  const int tid = threadIdx.x;
  const int base = tid * SCAN_C;
  int local[SCAN_C];
  int s = 0;
#pragma unroll
  for (int j = 0; j < SCAN_C; ++j) {
    int idx = base + j;
    int c = (idx < NN) ? cnt_i[idx] : 0;
    local[j] = s;  // exclusive within chunk
    s += c;
  }
  tot[tid] = s;
  __syncthreads();
  for (int off = 1; off < SCAN_T; off <<= 1) {
    int v = (tid >= off) ? tot[tid - off] : 0;
    __syncthreads();
    tot[tid] += v;
    __syncthreads();
  }
  int chunk_base = (tid == 0) ? 0 : tot[tid - 1];
#pragma unroll
  for (int j = 0; j < SCAN_C; ++j) {
    int idx = base + j;
    if (idx < NN) {
      int o = chunk_base + local[j];
      eoff[idx] = o;
      cursor[idx] = o;
    }
  }
  if (tid == SCAN_T - 1) eoff[NN] = tot[tid];
}

__global__ void csr_fill_k(const int* __restrict__ col,
                           int* __restrict__ cursor, int* __restrict__ elist) {
  int e = blockIdx.x * 256 + threadIdx.x;
  if (e < NE) {
    int pos = atomicAdd(&cursor[col[e]], 1);
    elist[pos] = e;
  }
}

// Gather-sum of eout rows per col-node; fused mean. Zero atomics.
__global__ __launch_bounds__(128) void gather_k(
    const float* __restrict__ eout, const int* __restrict__ eoff,
    const int* __restrict__ elist, float* __restrict__ agg) {
  const int v = blockIdx.x;
  const int d = threadIdx.x;
  const int s0 = eoff[v], s1 = eoff[v + 1];
  float s = 0.f;
  int j = s0;
  for (; j + 3 < s1; j += 4) {
    int e0 = elist[j], e1 = elist[j + 1], e2 = elist[j + 2], e3 = elist[j + 3];
    float x0 = eout[(size_t)e0 * 128 + d];
    float x1 = eout[(size_t)e1 * 128 + d];
    float x2 = eout[(size_t)e2 * 128 + d];
    float x3 = eout[(size_t)e3 * 128 + d];
    s += x0 + x1 + x2 + x3;
  }
  for (; j < s1; ++j) s += eout[(size_t)elist[j] * 128 + d];
  float c = (float)(s1 - s0);
  c = c > 1.f ? c : 1.f;
  agg[(size_t)v * 128 + d] = s / c;
}

// Per-graph edge sums: full LDS histogram per block, non-atomic flush to
// eg_part[block][g][d]; reduced by eg_reduce_k. Zero global atomics.
#define EGB 256
__global__ __launch_bounds__(256) void eg_hist_k(
    const float* __restrict__ eout, const int* __restrict__ row,
    const int* __restrict__ batch, float* __restrict__ eg_part) {
  __shared__ float part[NG * 128];  // 64 KB
  const int tid = threadIdx.x;
  for (int i = tid; i < NG * 128; i += 256) part[i] = 0.f;
  __syncthreads();
  const int es = tid >> 5;  // 0..7
  const int dl = tid & 31;
  for (int base = blockIdx.x * 8; base < NE; base += EGB * 8) {
    int e = base + es;
    if (e < NE) {
      int g = batch[row[e]];
      const float* ep = eout + (size_t)e * 128 + dl;
      float* pp = &part[g * 128 + dl];
      atomicAdd(pp, ep[0]);
      atomicAdd(pp + 32, ep[32]);
      atomicAdd(pp + 64, ep[64]);
      atomicAdd(pp + 96, ep[96]);
    }
  }
  __syncthreads();
  float* dst = eg_part + (size_t)blockIdx.x * (NG * 128);
  for (int i = tid; i < NG * 128; i += 256) dst[i] = part[i];
}

__global__ void eg_reduce_k(const float* __restrict__ eg_part,
                            float* __restrict__ eg_final) {
  const int g = blockIdx.x, d = threadIdx.x;
  float s = 0.f;
  for (int b = 0; b < EGB; ++b)
    s += eg_part[(size_t)b * (NG * 128) + g * 128 + d];
  eg_final[g * 128 + d] = s;
}

__global__ void node_gagg_k(const float* __restrict__ nout,
                            const int* __restrict__ batch,
                            float* __restrict__ ngsum,
                            float* __restrict__ cnt_gn) {
  int n = blockIdx.x, d = threadIdx.x;
  int g = batch[n];
  float v = nout[(size_t)n * 128 + d];
  atomicAdd(&ngsum[((size_t)(n & 63) * 128 + g) * 128 + d], v);
  if (d == 0) atomicAdd(&cnt_gn[g], 1.f);
}

__global__ void gin_k(const float* __restrict__ ngsum,
                      const float* __restrict__ eg_final,
                      const float* __restrict__ cnt_gn,
                      const float* __restrict__ cnt_ge,
                      const float* __restrict__ u, float* __restrict__ g_in) {
  int g = blockIdx.x, d = threadIdx.x;
  float ns = 0.f;
  for (int r = 0; r < 64; ++r) ns += ngsum[((size_t)r * 128 + g) * 128 + d];
  float es = eg_final[g * 128 + d];
  float cn = cnt_gn[g]; cn = cn > 1.f ? cn : 1.f;
  float ce = cnt_ge[g]; ce = ce > 1.f ? ce : 1.f;
  g_in[g * 384 + d] = u[g * 128 + d];
  g_in[g * 384 + 128 + d] = ns / cn;
  g_in[g * 384 + 256 + d] = es / ce;
}

extern "C" void kernel_launch(void* const* d_in, const int* in_sizes, int n_in,
                              void* d_out, int out_size, void* d_ws,
                              size_t ws_size, hipStream_t stream) {
  (void)in_sizes; (void)n_in; (void)out_size; (void)ws_size;
  const float* nodes = (const float*)d_in[0];
  const int* eidx = (const int*)d_in[1];
  const float* eattr = (const float*)d_in[2];
  const float* u = (const float*)d_in[3];
  const int* batch = (const int*)d_in[4];
  const float* W[9] = {(const float*)d_in[5],  (const float*)d_in[7],
                       (const float*)d_in[9],  (const float*)d_in[11],
                       (const float*)d_in[13], (const float*)d_in[15],
                       (const float*)d_in[17], (const float*)d_in[19],
                       (const float*)d_in[21]};
  const float* Bi[9] = {(const float*)d_in[6],  (const float*)d_in[8],
                        (const float*)d_in[10], (const float*)d_in[12],
                        (const float*)d_in[14], (const float*)d_in[16],
                        (const float*)d_in[18], (const float*)d_in[20],
                        (const float*)d_in[22]};
  const int* row = eidx;
  const int* col = eidx + NE;

  char* p = (char*)d_ws;
  auto alloc = [&](size_t b) {
    void* r = (void*)p;
    p += (b + 255) & ~(size_t)255;
    return r;
  };
  float* h_e0 = (float*)alloc((size_t)NE * 256 * 4);  // f32 hidden, in-place L1

  // Weight slices (pre-split, transposed to [n][k]):
  //  0: W0[  0:128)  (-> Pr via nodes)      1: W0[128:256) (-> Pc via nodes)
  //  2: W0[256:384)  (edge L1 A-part)       3: W0[384:512) (-> Pu via u)
  //  4: W1            5: W2
  //  6: W3[  0:256)  (node L1 [nodes|agg])  7: W3[256:384) (-> Pun via u)
  //  8: W4            9: W5
  // 10: W6           11: W7                12: W8
  const int wk[13] = {128, 128, 128, 128, 256, 256, 256, 128, 256, 256, 384, 256, 256};
  const int wnn[13] = {256, 256, 256, 256, 256, 128, 256, 256, 256, 128, 256, 256, 128};
  const float* Wsrc[13] = {W[0],              W[0] + 128 * 256, W[0] + 256 * 256,
                           W[0] + 384 * 256,  W[1],             W[2],
                           W[3],              W[3] + 256 * 256, W[4],
                           W[5],              W[6],             W[7],
                           W[8]};
  bf16 *Wh[13], *Wl[13];
  for (int i = 0; i < 13; ++i) {
    Wh[i] = (bf16*)alloc((size_t)wk[i] * wnn[i] * 2);
    Wl[i] = (bf16*)alloc((size_t)wk[i] * wnn[i] * 2);
  }

  // Projection tables
  float* Pu = (float*)alloc((size_t)NG * 256 * 4);   // u @ W0d
  float* Pr = (float*)alloc((size_t)NN * 256 * 4);   // nodes @ W0a + Pu[batch]
  float* Pc = (float*)alloc((size_t)NN * 256 * 4);   // nodes @ W0b
  float* Pun = (float*)alloc((size_t)NG * 256 * 4);  // u @ W3c

  // CSR + aggregation buffers (non-zeroed unless in zero region)
  float* agg = (float*)alloc((size_t)NN * 128 * 4);
  int* eoff = (int*)alloc((size_t)(NN + 1) * 4);
  int* cursor = (int*)alloc((size_t)NN * 4);
  int* elist = (int*)alloc((size_t)NE * 4);
  float* eg_part = (float*)alloc((size_t)EGB * NG * 128 * 4);  // 16.8 MB
  float* eg_final = (float*)alloc((size_t)NG * 128 * 4);

  char* zero_base = p;
  int* cnt_i = (int*)alloc((size_t)NN * 4);
  float* ngsum = (float*)alloc((size_t)64 * 128 * 128 * 4);
  float* cnt_gn = (float*)alloc(512);
  float* cnt_ge = (float*)alloc(512);
  float* zeros = (float*)alloc(256 * 4);  // zero bias for projection GEMMs
  size_t zero_len = (size_t)(p - zero_base);
  float* g_in = (float*)alloc((size_t)NG * 384 * 4);
  float* h_g0 = (float*)alloc((size_t)NG * 256 * 4);
  float* h_n0 = h_e0;

  float* out_nodes = (float*)d_out;
  float* out_edges = out_nodes + (size_t)NN * 128;
  float* out_glob = out_nodes + (size_t)NN * 128 + (size_t)NE * 128;

  for (int i = 0; i < 13; ++i) {
    int tot = wk[i] * wnn[i];
    splitw_k<<<(tot + 255) / 256, 256, 0, stream>>>(Wsrc[i], Wh[i], Wl[i],
                                                    wk[i], wnn[i]);
  }
  hipMemsetAsync(zero_base, 0, zero_len, stream);

  const int gbE = (NE + 127) / 128;   // 2344
  const int gbN = (NN + 127) / 128;   // 235

  // ---- CSR build over col (needs only edge_index + batch) ----
  csr_cnt_k<<<256, 256, 0, stream>>>(col, row, batch, cnt_i, cnt_ge);
  scan_k<<<1, SCAN_T, 0, stream>>>(cnt_i, eoff, cursor);
  csr_fill_k<<<(NE + 255) / 256, 256, 0, stream>>>(col, cursor, elist);

  // ---- Projections (K=128 each) ----
  gemm_wide<0><<<1, 512, 0, stream>>>(u, Wh[3], Wl[3], zeros, Pu, NG, 128, 0,
                                      nullptr, nullptr, nullptr, nullptr,
                                      nullptr, nullptr);
  gemm_wide<2><<<gbN, 512, 0, stream>>>(nullptr, Wh[0], Wl[0], zeros, Pr, NN,
                                        128, 0, nodes, nullptr, Pu, nullptr,
                                        nullptr, batch);
  gemm_wide<0><<<gbN, 512, 0, stream>>>(nodes, Wh[1], Wl[1], zeros, Pc, NN,
                                        128, 0, nullptr, nullptr, nullptr,
                                        nullptr, nullptr, nullptr);
  gemm_wide<0><<<1, 512, 0, stream>>>(u, Wh[7], Wl[7], zeros, Pun, NG, 128, 0,
                                      nullptr, nullptr, nullptr, nullptr,
                                      nullptr, nullptr);

  // ---- Edge MLP: (eattr @ W0c + Pr[row] + Pc[col] + b0) -> 256 -> 128 ----
  gemm_wide<1><<<gbE, 512, 0, stream>>>(eattr, Wh[2], Wl[2], Bi[0], h_e0, NE,
                                        128, 1, Pr, Pc, nullptr, row, col,
                                        nullptr);
  gemm_wide<0><<<gbE, 512, 0, stream>>>(h_e0, Wh[4], Wl[4], Bi[1], h_e0, NE,
                                        256, 1, nullptr, nullptr, nullptr,
                                        nullptr, nullptr, nullptr);
  gemm128<<<dim3(gbE, 1), 256, 0, stream>>>(h_e0, Wh[5], Wl[5], Bi[2],
                                            out_edges, NE, 128, 256, 0);

  // ---- Aggregations: atomic-free gather + histogram ----
  gather_k<<<NN, 128, 0, stream>>>(out_edges, eoff, elist, agg);
  eg_hist_k<<<EGB, 256, 0, stream>>>(out_edges, row, batch, eg_part);
  eg_reduce_k<<<NG, 128, 0, stream>>>(eg_part, eg_final);

  // ---- Node MLP: ([nodes|agg] @ W3ab + Pun[batch] + b3) -> 256 -> 128 ----
  gemm_wide<2><<<gbN, 512, 0, stream>>>(nullptr, Wh[6], Wl[6], Bi[3], h_n0, NN,
                                        256, 1, nodes, agg, Pun, nullptr,
                                        nullptr, batch);
  gemm_wide<0><<<gbN, 512, 0, stream>>>(h_n0, Wh[8], Wl[8], Bi[4], h_n0, NN,
                                        256, 1, nullptr, nullptr, nullptr,
                                        nullptr, nullptr, nullptr);
  gemm128<<<dim3(gbN, 1), 256, 0, stream>>>(h_n0, Wh[9], Wl[9], Bi[5],
                                            out_nodes, NN, 128, 256, 0);

  node_gagg_k<<<NN, 128, 0, stream>>>(out_nodes, batch, ngsum, cnt_gn);
  gin_k<<<NG, 128, 0, stream>>>(ngsum, eg_final, cnt_gn, cnt_ge, u, g_in);

  // ---- Global MLP: 384 -> 256 -> 256 -> 128 ----
  gemm_wide<0><<<1, 512, 0, stream>>>(g_in, Wh[10], Wl[10], Bi[6], h_g0, NG,
                                      384, 1, nullptr, nullptr, nullptr,
                                      nullptr, nullptr, nullptr);
  gemm_wide<0><<<1, 512, 0, stream>>>(h_g0, Wh[11], Wl[11], Bi[7], h_g0, NG,
                                      256, 1, nullptr, nullptr, nullptr,
                                      nullptr, nullptr, nullptr);
  gemm128<<<dim3(1, 1), 256, 0, stream>>>(h_g0, Wh[12], Wl[12], Bi[8],
                                          out_glob, NG, 128, 256, 0);
}

// Round 3
// 1358.038 us; speedup vs baseline: 1.1001x; 1.1001x over previous
//
#include <hip/hip_runtime.h>
#include <stdint.h>

typedef __bf16 bf16;
typedef __bf16 bf16x8 __attribute__((ext_vector_type(8)));
typedef float f32x4 __attribute__((ext_vector_type(4)));

#define NN 30000
#define NE 300000
#define NG 128
#define DD 128

// Hf layout: slab s (32 k-values) x 64 rows x stride 36 (pad -> 2-way banks)
#define HROW 36
#define HSLAB (64 * HROW)

// ---------------------------------------------------------------------------
// Fused 3-layer MLP: L1(K1->256,relu) -> L2(256->256,relu) -> L3(256->128).
// Hidden activations stay in LDS (f32); A-frags split to bf16 h/l at read;
// B-frags streamed from global (L2-resident weights). No barriers in K-loops.
// MODE 1 (edge): A=eattr[M,128], epilogue1 += Pr[row[m]] + Pc[col[m]]
// MODE 2 (node): A-halves = s0=nodes, s1=agg; epilogue1 += Pun[batch[m]]
// ---------------------------------------------------------------------------
template <int NF, int K>
__device__ __forceinline__ void mfma_layer(const float* __restrict__ Hf,
                                           const bf16* __restrict__ Wh,
                                           const bf16* __restrict__ Wl,
                                           int nbase, int lr, int qh,
                                           f32x4 (&acc)[4][4]) {
  const int q8 = qh * 8;
#pragma unroll
  for (int s = 0; s < K / 32; ++s) {
    bf16x8 afh[4], afl[4];
#pragma unroll
    for (int mi = 0; mi < 4; ++mi) {
      int mrow = mi * 16 + lr;
      const float* ap = &Hf[s * HSLAB + mrow * HROW + q8];
      f32x4 x0 = *(const f32x4*)ap;
      f32x4 x1 = *(const f32x4*)(ap + 4);
      bf16x8 h, l;
#pragma unroll
      for (int i = 0; i < 4; ++i) {
        float x = x0[i]; bf16 hh = (bf16)x; h[i] = hh; l[i] = (bf16)(x - (float)hh);
        x = x1[i]; hh = (bf16)x; h[4 + i] = hh; l[4 + i] = (bf16)(x - (float)hh);
      }
      afh[mi] = h;
      afl[mi] = l;
    }
#pragma unroll
    for (int ni = 0; ni < NF; ++ni) {
      int nrow = nbase + ni * 16 + lr;
      bf16x8 bh = *(const bf16x8*)(Wh + (size_t)nrow * K + s * 32 + q8);
      bf16x8 bl = *(const bf16x8*)(Wl + (size_t)nrow * K + s * 32 + q8);
#pragma unroll
      for (int mi = 0; mi < 4; ++mi) {
        acc[mi][ni] = __builtin_amdgcn_mfma_f32_16x16x32_bf16(afl[mi], bh, acc[mi][ni], 0, 0, 0);
        acc[mi][ni] = __builtin_amdgcn_mfma_f32_16x16x32_bf16(afh[mi], bl, acc[mi][ni], 0, 0, 0);
        acc[mi][ni] = __builtin_amdgcn_mfma_f32_16x16x32_bf16(afh[mi], bh, acc[mi][ni], 0, 0, 0);
      }
    }
  }
}

template <int MODE>
__global__ __launch_bounds__(256, 2) void mlp_fused(
    const float* __restrict__ A,
    const bf16* __restrict__ W1h, const bf16* __restrict__ W1l, const float* __restrict__ b1,
    const bf16* __restrict__ W2h, const bf16* __restrict__ W2l, const float* __restrict__ b2,
    const bf16* __restrict__ W3h, const bf16* __restrict__ W3l, const float* __restrict__ b3,
    float* __restrict__ C, int M,
    const float* __restrict__ s0, const float* __restrict__ s1,
    const float* __restrict__ s2, const int* __restrict__ i0,
    const int* __restrict__ i1, const int* __restrict__ i2) {
  __shared__ float Hf[8 * HSLAB];  // 72 KB
  const int tid = threadIdx.x;
  const int wn = tid >> 6, lane = tid & 63;
  const int lr = lane & 15, qh = lane >> 4;
  const int m0 = blockIdx.x * 64;
  constexpr int K1 = (MODE == 1) ? 128 : 256;

  // ---- stage layer-1 A into Hf slabs [0, K1/32) ----
  {
    const int ar = tid >> 2;       // 0..63
    const int gq = tid & 3;        // k-group
    int gm = m0 + ar;
    if (gm > M - 1) gm = M - 1;
#pragma unroll
    for (int s = 0; s < K1 / 32; ++s) {
      int k = s * 32 + gq * 8;
      const float* src;
      if (MODE == 1) src = A + (size_t)gm * 128 + k;
      else src = (k < 128) ? (s0 + (size_t)gm * 128 + k)
                           : (s1 + (size_t)gm * 128 + (k - 128));
      f32x4 v0 = *(const f32x4*)src;
      f32x4 v1 = *(const f32x4*)(src + 4);
      float* dst = &Hf[s * HSLAB + ar * HROW + gq * 8];
      *(f32x4*)dst = v0;
      *(f32x4*)(dst + 4) = v1;
    }
  }
  __syncthreads();

  f32x4 acc[4][4];
  const f32x4 zz = {0.f, 0.f, 0.f, 0.f};

  // ---- layer 1 ----
#pragma unroll
  for (int a = 0; a < 4; ++a)
#pragma unroll
    for (int b = 0; b < 4; ++b) acc[a][b] = zz;
  mfma_layer<4, K1>(Hf, W1h, W1l, wn * 64, lr, qh, acc);
  __syncthreads();  // all reads of staged A done

  {
    float bb[4];
#pragma unroll
    for (int ni = 0; ni < 4; ++ni) bb[ni] = b1[wn * 64 + ni * 16 + lr];
    const int rq = qh * 4;
#pragma unroll
    for (int mi = 0; mi < 4; ++mi) {
#pragma unroll
      for (int r = 0; r < 4; ++r) {
        int m = mi * 16 + rq + r;
        int gm = m0 + m;
        if (gm > M - 1) gm = M - 1;
        const float* p0;
        const float* p1 = nullptr;
        if (MODE == 1) {
          p0 = s0 + (size_t)i0[gm] * 256;
          p1 = s1 + (size_t)i1[gm] * 256;
        } else {
          p0 = s2 + (size_t)i2[gm] * 256;
        }
#pragma unroll
        for (int ni = 0; ni < 4; ++ni) {
          int n = wn * 64 + ni * 16 + lr;
          float v = acc[mi][ni][r] + bb[ni] + p0[n];
          if (MODE == 1) v += p1[n];
          v = v > 0.f ? v : 0.f;
          Hf[(n >> 5) * HSLAB + m * HROW + (n & 31)] = v;
        }
      }
    }
  }
  __syncthreads();

  // ---- layer 2 ----
#pragma unroll
  for (int a = 0; a < 4; ++a)
#pragma unroll
    for (int b = 0; b < 4; ++b) acc[a][b] = zz;
  mfma_layer<4, 256>(Hf, W2h, W2l, wn * 64, lr, qh, acc);
  __syncthreads();  // all reads of h1 done

  {
    float bb[4];
#pragma unroll
    for (int ni = 0; ni < 4; ++ni) bb[ni] = b2[wn * 64 + ni * 16 + lr];
    const int rq = qh * 4;
#pragma unroll
    for (int mi = 0; mi < 4; ++mi) {
#pragma unroll
      for (int r = 0; r < 4; ++r) {
        int m = mi * 16 + rq + r;
#pragma unroll
        for (int ni = 0; ni < 4; ++ni) {
          int n = wn * 64 + ni * 16 + lr;
          float v = acc[mi][ni][r] + bb[ni];
          v = v > 0.f ? v : 0.f;
          Hf[(n >> 5) * HSLAB + m * HROW + (n & 31)] = v;
        }
      }
    }
  }
  __syncthreads();

  // ---- layer 3 (N=128, each wave owns 32 cols) ----
#pragma unroll
  for (int a = 0; a < 4; ++a)
#pragma unroll
    for (int b = 0; b < 4; ++b) acc[a][b] = zz;
  mfma_layer<2, 256>(Hf, W3h, W3l, wn * 32, lr, qh, acc);

  {
    float bb[2];
#pragma unroll
    for (int ni = 0; ni < 2; ++ni) bb[ni] = b3[wn * 32 + ni * 16 + lr];
    const int rq = qh * 4;
#pragma unroll
    for (int mi = 0; mi < 4; ++mi) {
#pragma unroll
      for (int r = 0; r < 4; ++r) {
        int m = m0 + mi * 16 + rq + r;
        if (m < M) {
#pragma unroll
          for (int ni = 0; ni < 2; ++ni) {
            int n = wn * 32 + ni * 16 + lr;
            C[(size_t)m * 128 + n] = acc[mi][ni][r] + bb[ni];
          }
        }
      }
    }
  }
}

// ---------------------------------------------------------------------------
// Wide GEMM (projections + global MLP), unchanged structure.
// ---------------------------------------------------------------------------
template <int MODE>
__global__ __launch_bounds__(512) void gemm_wide(
    const float* __restrict__ A, const bf16* __restrict__ Bh,
    const bf16* __restrict__ Bl, const float* __restrict__ bias,
    float* __restrict__ C, int M, int K, int do_relu,
    const float* __restrict__ s0, const float* __restrict__ s1,
    const float* __restrict__ s2, const int* __restrict__ i0,
    const int* __restrict__ i1, const int* __restrict__ i2) {
  __shared__ bf16 Ash[128 * 32];
  __shared__ bf16 Asl[128 * 32];
  __shared__ bf16 Bsh[256 * 32];
  __shared__ bf16 Bsl[256 * 32];
  const int tid = threadIdx.x;
  const int w = tid >> 6, lane = tid & 63;
  const int wm = w >> 2, wn = w & 3;
  const int m0 = blockIdx.x * 128;
  const int ar = tid >> 2;
  const int k8 = (tid & 3) * 8;

  int gm = m0 + ar;
  if (gm > M - 1) gm = M - 1;

  f32x4 acc[4][4];
#pragma unroll
  for (int a = 0; a < 4; ++a)
#pragma unroll
    for (int b = 0; b < 4; ++b) acc[a][b] = {0.f, 0.f, 0.f, 0.f};

  for (int k0 = 0; k0 < K; k0 += 32) {
    const float* ga;
    if (MODE == 2) {
      int kk = k0 + k8;
      ga = (kk < DD) ? (s0 + (size_t)gm * DD + kk)
                     : (s1 + (size_t)gm * DD + (kk - DD));
    } else {
      ga = A + (size_t)gm * K + k0 + k8;
    }
    f32x4 a0 = *(const f32x4*)ga;
    f32x4 a1 = *(const f32x4*)(ga + 4);
    bf16x8 vh, vl;
#pragma unroll
    for (int i = 0; i < 4; ++i) {
      float x = a0[i];
      bf16 h = (bf16)x;
      vh[i] = h;
      vl[i] = (bf16)(x - (float)h);
    }
#pragma unroll
    for (int i = 0; i < 4; ++i) {
      float x = a1[i];
      bf16 h = (bf16)x;
      vh[4 + i] = h;
      vl[4 + i] = (bf16)(x - (float)h);
    }
    bf16x8 bh0 = *(const bf16x8*)(Bh + (size_t)ar * K + k0 + k8);
    bf16x8 bl0 = *(const bf16x8*)(Bl + (size_t)ar * K + k0 + k8);
    bf16x8 bh1 = *(const bf16x8*)(Bh + (size_t)(ar + 128) * K + k0 + k8);
    bf16x8 bl1 = *(const bf16x8*)(Bl + (size_t)(ar + 128) * K + k0 + k8);

    __syncthreads();
    *(bf16x8*)&Ash[ar * 32 + k8] = vh;
    *(bf16x8*)&Asl[ar * 32 + k8] = vl;
    *(bf16x8*)&Bsh[ar * 32 + k8] = bh0;
    *(bf16x8*)&Bsl[ar * 32 + k8] = bl0;
    *(bf16x8*)&Bsh[(ar + 128) * 32 + k8] = bh1;
    *(bf16x8*)&Bsl[(ar + 128) * 32 + k8] = bl1;
    __syncthreads();

    const int lr = lane & 15, q8 = (lane >> 4) * 8;
    bf16x8 afh[4], afl[4], bfh[4], bfl[4];
#pragma unroll
    for (int mi = 0; mi < 4; ++mi) {
      afh[mi] = *(const bf16x8*)&Ash[(wm * 64 + mi * 16 + lr) * 32 + q8];
      afl[mi] = *(const bf16x8*)&Asl[(wm * 64 + mi * 16 + lr) * 32 + q8];
    }
#pragma unroll
    for (int ni = 0; ni < 4; ++ni) {
      bfh[ni] = *(const bf16x8*)&Bsh[(wn * 64 + ni * 16 + lr) * 32 + q8];
      bfl[ni] = *(const bf16x8*)&Bsl[(wn * 64 + ni * 16 + lr) * 32 + q8];
    }
#pragma unroll
    for (int mi = 0; mi < 4; ++mi)
#pragma unroll
      for (int ni = 0; ni < 4; ++ni) {
        acc[mi][ni] = __builtin_amdgcn_mfma_f32_16x16x32_bf16(afl[mi], bfh[ni], acc[mi][ni], 0, 0, 0);
        acc[mi][ni] = __builtin_amdgcn_mfma_f32_16x16x32_bf16(afh[mi], bfl[ni], acc[mi][ni], 0, 0, 0);
        acc[mi][ni] = __builtin_amdgcn_mfma_f32_16x16x32_bf16(afh[mi], bfh[ni], acc[mi][ni], 0, 0, 0);
      }
  }

  const int lr = lane & 15;
  const int rq = (lane >> 4) * 4;
  float bb[4];
#pragma unroll
  for (int ni = 0; ni < 4; ++ni) bb[ni] = bias[wn * 64 + ni * 16 + lr];
#pragma unroll
  for (int mi = 0; mi < 4; ++mi) {
#pragma unroll
    for (int r = 0; r < 4; ++r) {
      int m = m0 + wm * 64 + mi * 16 + rq + r;
      if (m >= M) continue;
      const float* p2 = nullptr;
      if (MODE == 2) p2 = s2 + (size_t)i2[m] * 256;
#pragma unroll
      for (int ni = 0; ni < 4; ++ni) {
        int n = wn * 64 + ni * 16 + lr;
        float v = acc[mi][ni][r] + bb[ni];
        if (MODE == 2) v += p2[n];
        if (do_relu) v = v > 0.f ? v : 0.f;
        C[(size_t)m * 256 + n] = v;
      }
    }
  }
}

// 128x128-tile GEMM (global L3 only).
__global__ __launch_bounds__(256) void gemm128(
    const float* __restrict__ A, const bf16* __restrict__ Bh,
    const bf16* __restrict__ Bl, const float* __restrict__ bias,
    float* __restrict__ C, int M, int N, int K, int do_relu) {
  __shared__ bf16 Ash[128 * 32];
  __shared__ bf16 Asl[128 * 32];
  __shared__ bf16 Bsh[128 * 32];
  __shared__ bf16 Bsl[128 * 32];
  const int tid = threadIdx.x;
  const int w = tid >> 6, lane = tid & 63;
  const int wm = w >> 1, wn = w & 1;
  const int m0 = blockIdx.x * 128, n0 = blockIdx.y * 128;
  const int ar = tid >> 2;
  const int k8 = (tid & 3) * 8;

  int gmA0 = m0 + ar;      if (gmA0 > M - 1) gmA0 = M - 1;
  int gmA1 = m0 + ar + 64; if (gmA1 > M - 1) gmA1 = M - 1;

  f32x4 acc[4][4];
#pragma unroll
  for (int a = 0; a < 4; ++a)
#pragma unroll
    for (int b = 0; b < 4; ++b) acc[a][b] = {0.f, 0.f, 0.f, 0.f};

  for (int k0 = 0; k0 < K; k0 += 32) {
    f32x4 a00 = *(const f32x4*)(A + (size_t)gmA0 * K + k0 + k8);
    f32x4 a01 = *(const f32x4*)(A + (size_t)gmA0 * K + k0 + k8 + 4);
    f32x4 a10 = *(const f32x4*)(A + (size_t)gmA1 * K + k0 + k8);
    f32x4 a11 = *(const f32x4*)(A + (size_t)gmA1 * K + k0 + k8 + 4);
    bf16x8 v0h, v0l, v1h, v1l;
#pragma unroll
    for (int i = 0; i < 4; ++i) {
      float x = a00[i]; bf16 h = (bf16)x; v0h[i] = h; v0l[i] = (bf16)(x - (float)h);
      x = a01[i]; h = (bf16)x; v0h[4 + i] = h; v0l[4 + i] = (bf16)(x - (float)h);
      x = a10[i]; h = (bf16)x; v1h[i] = h; v1l[i] = (bf16)(x - (float)h);
      x = a11[i]; h = (bf16)x; v1h[4 + i] = h; v1l[4 + i] = (bf16)(x - (float)h);
    }
    bf16x8 bh0 = *(const bf16x8*)(Bh + (size_t)(n0 + ar) * K + k0 + k8);
    bf16x8 bl0 = *(const bf16x8*)(Bl + (size_t)(n0 + ar) * K + k0 + k8);
    bf16x8 bh1 = *(const bf16x8*)(Bh + (size_t)(n0 + ar + 64) * K + k0 + k8);
    bf16x8 bl1 = *(const bf16x8*)(Bl + (size_t)(n0 + ar + 64) * K + k0 + k8);

    __syncthreads();
    *(bf16x8*)&Ash[ar * 32 + k8] = v0h;
    *(bf16x8*)&Asl[ar * 32 + k8] = v0l;
    *(bf16x8*)&Ash[(ar + 64) * 32 + k8] = v1h;
    *(bf16x8*)&Asl[(ar + 64) * 32 + k8] = v1l;
    *(bf16x8*)&Bsh[ar * 32 + k8] = bh0;
    *(bf16x8*)&Bsl[ar * 32 + k8] = bl0;
    *(bf16x8*)&Bsh[(ar + 64) * 32 + k8] = bh1;
    *(bf16x8*)&Bsl[(ar + 64) * 32 + k8] = bl1;
    __syncthreads();

    const int lr = lane & 15, q8 = (lane >> 4) * 8;
    bf16x8 afh[4], afl[4], bfh[4], bfl[4];
#pragma unroll
    for (int mi = 0; mi < 4; ++mi) {
      afh[mi] = *(const bf16x8*)&Ash[(wm * 64 + mi * 16 + lr) * 32 + q8];
      afl[mi] = *(const bf16x8*)&Asl[(wm * 64 + mi * 16 + lr) * 32 + q8];
    }
#pragma unroll
    for (int ni = 0; ni < 4; ++ni) {
      bfh[ni] = *(const bf16x8*)&Bsh[(wn * 64 + ni * 16 + lr) * 32 + q8];
      bfl[ni] = *(const bf16x8*)&Bsl[(wn * 64 + ni * 16 + lr) * 32 + q8];
    }
#pragma unroll
    for (int mi = 0; mi < 4; ++mi)
#pragma unroll
      for (int ni = 0; ni < 4; ++ni) {
        acc[mi][ni] = __builtin_amdgcn_mfma_f32_16x16x32_bf16(afl[mi], bfh[ni], acc[mi][ni], 0, 0, 0);
        acc[mi][ni] = __builtin_amdgcn_mfma_f32_16x16x32_bf16(afh[mi], bfl[ni], acc[mi][ni], 0, 0, 0);
        acc[mi][ni] = __builtin_amdgcn_mfma_f32_16x16x32_bf16(afh[mi], bfh[ni], acc[mi][ni], 0, 0, 0);
      }
  }

  const int lr = lane & 15;
  const int rq = (lane >> 4) * 4;
#pragma unroll
  for (int ni = 0; ni < 4; ++ni) {
    int n = n0 + wn * 64 + ni * 16 + lr;
    float bb = bias[n];
#pragma unroll
    for (int mi = 0; mi < 4; ++mi) {
#pragma unroll
      for (int r = 0; r < 4; ++r) {
        int m = m0 + wm * 64 + mi * 16 + rq + r;
        if (m < M) {
          float v = acc[mi][ni][r] + bb;
          if (do_relu) v = v > 0.f ? v : 0.f;
          C[(size_t)m * N + n] = v;
        }
      }
    }
  }
}

__global__ void splitw_k(const float* __restrict__ W, bf16* __restrict__ Wh,
                         bf16* __restrict__ Wl, int K, int N) {
  int i = blockIdx.x * 256 + threadIdx.x;
  if (i < K * N) {
    int k = i / N, n = i % N;
    float x = W[i];
    bf16 h = (bf16)x;
    Wh[(size_t)n * K + k] = h;
    Wl[(size_t)n * K + k] = (bf16)(x - (float)h);
  }
}

// ---------------------------------------------------------------------------
// CSR build + atomic-free aggregations (unchanged from round 2).
// ---------------------------------------------------------------------------
__global__ __launch_bounds__(256) void csr_cnt_k(
    const int* __restrict__ col, const int* __restrict__ row,
    const int* __restrict__ batch, int* __restrict__ cnt_i,
    float* __restrict__ cnt_ge) {
  __shared__ float hist[NG];
  const int tid = threadIdx.x;
  if (tid < NG) hist[tid] = 0.f;
  __syncthreads();
  for (int e = blockIdx.x * 256 + tid; e < NE; e += gridDim.x * 256) {
    atomicAdd(&cnt_i[col[e]], 1);
    atomicAdd(&hist[batch[row[e]]], 1.f);
  }
  __syncthreads();
  if (tid < NG) atomicAdd(&cnt_ge[tid], hist[tid]);
}

#define SCAN_T 1024
#define SCAN_C 30
__global__ __launch_bounds__(1024) void scan_k(const int* __restrict__ cnt_i,
                                               int* __restrict__ eoff,
                                               int* __restrict__ cursor) {
  __shared__ int tot[SCAN_T];
  const int tid = threadIdx.x;
  const int base = tid * SCAN_C;
  int local[SCAN_C];
  int s = 0;
#pragma unroll
  for (int j = 0; j < SCAN_C; ++j) {
    int idx = base + j;
    int c = (idx < NN) ? cnt_i[idx] : 0;
    local[j] = s;
    s += c;
  }
  tot[tid] = s;
  __syncthreads();
  for (int off = 1; off < SCAN_T; off <<= 1) {
    int v = (tid >= off) ? tot[tid - off] : 0;
    __syncthreads();
    tot[tid] += v;
    __syncthreads();
  }
  int chunk_base = (tid == 0) ? 0 : tot[tid - 1];
#pragma unroll
  for (int j = 0; j < SCAN_C; ++j) {
    int idx = base + j;
    if (idx < NN) {
      int o = chunk_base + local[j];
      eoff[idx] = o;
      cursor[idx] = o;
    }
  }
  if (tid == SCAN_T - 1) eoff[NN] = tot[tid];
}

__global__ void csr_fill_k(const int* __restrict__ col,
                           int* __restrict__ cursor, int* __restrict__ elist) {
  int e = blockIdx.x * 256 + threadIdx.x;
  if (e < NE) {
    int pos = atomicAdd(&cursor[col[e]], 1);
    elist[pos] = e;
  }
}

__global__ __launch_bounds__(128) void gather_k(
    const float* __restrict__ eout, const int* __restrict__ eoff,
    const int* __restrict__ elist, float* __restrict__ agg) {
  const int v = blockIdx.x;
  const int d = threadIdx.x;
  const int s0 = eoff[v], s1 = eoff[v + 1];
  float s = 0.f;
  int j = s0;
  for (; j + 3 < s1; j += 4) {
    int e0 = elist[j], e1 = elist[j + 1], e2 = elist[j + 2], e3 = elist[j + 3];
    float x0 = eout[(size_t)e0 * 128 + d];
    float x1 = eout[(size_t)e1 * 128 + d];
    float x2 = eout[(size_t)e2 * 128 + d];
    float x3 = eout[(size_t)e3 * 128 + d];
    s += x0 + x1 + x2 + x3;
  }
  for (; j < s1; ++j) s += eout[(size_t)elist[j] * 128 + d];
  float c = (float)(s1 - s0);
  c = c > 1.f ? c : 1.f;
  agg[(size_t)v * 128 + d] = s / c;
}

#define EGB 256
__global__ __launch_bounds__(256) void eg_hist_k(
    const float* __restrict__ eout, const int* __restrict__ row,
    const int* __restrict__ batch, float* __restrict__ eg_part) {
  __shared__ float part[NG * 128];  // 64 KB
  const int tid = threadIdx.x;
  for (int i = tid; i < NG * 128; i += 256) part[i] = 0.f;
  __syncthreads();
  const int es = tid >> 5;
  const int dl = tid & 31;
  for (int base = blockIdx.x * 8; base < NE; base += EGB * 8) {
    int e = base + es;
    if (e < NE) {
      int g = batch[row[e]];
      const float* ep = eout + (size_t)e * 128 + dl;
      float* pp = &part[g * 128 + dl];
      atomicAdd(pp, ep[0]);
      atomicAdd(pp + 32, ep[32]);
      atomicAdd(pp + 64, ep[64]);
      atomicAdd(pp + 96, ep[96]);
    }
  }
  __syncthreads();
  float* dst = eg_part + (size_t)blockIdx.x * (NG * 128);
  for (int i = tid; i < NG * 128; i += 256) dst[i] = part[i];
}

__global__ void eg_reduce_k(const float* __restrict__ eg_part,
                            float* __restrict__ eg_final) {
  const int g = blockIdx.x, d = threadIdx.x;
  float s = 0.f;
  for (int b = 0; b < EGB; ++b)
    s += eg_part[(size_t)b * (NG * 128) + g * 128 + d];
  eg_final[g * 128 + d] = s;
}

__global__ void node_gagg_k(const float* __restrict__ nout,
                            const int* __restrict__ batch,
                            float* __restrict__ ngsum,
                            float* __restrict__ cnt_gn) {
  int n = blockIdx.x, d = threadIdx.x;
  int g = batch[n];
  float v = nout[(size_t)n * 128 + d];
  atomicAdd(&ngsum[((size_t)(n & 63) * 128 + g) * 128 + d], v);
  if (d == 0) atomicAdd(&cnt_gn[g], 1.f);
}

__global__ void gin_k(const float* __restrict__ ngsum,
                      const float* __restrict__ eg_final,
                      const float* __restrict__ cnt_gn,
                      const float* __restrict__ cnt_ge,
                      const float* __restrict__ u, float* __restrict__ g_in) {
  int g = blockIdx.x, d = threadIdx.x;
  float ns = 0.f;
  for (int r = 0; r < 64; ++r) ns += ngsum[((size_t)r * 128 + g) * 128 + d];
  float es = eg_final[g * 128 + d];
  float cn = cnt_gn[g]; cn = cn > 1.f ? cn : 1.f;
  float ce = cnt_ge[g]; ce = ce > 1.f ? ce : 1.f;
  g_in[g * 384 + d] = u[g * 128 + d];
  g_in[g * 384 + 128 + d] = ns / cn;
  g_in[g * 384 + 256 + d] = es / ce;
}

extern "C" void kernel_launch(void* const* d_in, const int* in_sizes, int n_in,
                              void* d_out, int out_size, void* d_ws,
                              size_t ws_size, hipStream_t stream) {
  (void)in_sizes; (void)n_in; (void)out_size; (void)ws_size;
  const float* nodes = (const float*)d_in[0];
  const int* eidx = (const int*)d_in[1];
  const float* eattr = (const float*)d_in[2];
  const float* u = (const float*)d_in[3];
  const int* batch = (const int*)d_in[4];
  const float* W[9] = {(const float*)d_in[5],  (const float*)d_in[7],
                       (const float*)d_in[9],  (const float*)d_in[11],
                       (const float*)d_in[13], (const float*)d_in[15],
                       (const float*)d_in[17], (const float*)d_in[19],
                       (const float*)d_in[21]};
  const float* Bi[9] = {(const float*)d_in[6],  (const float*)d_in[8],
                        (const float*)d_in[10], (const float*)d_in[12],
                        (const float*)d_in[14], (const float*)d_in[16],
                        (const float*)d_in[18], (const float*)d_in[20],
                        (const float*)d_in[22]};
  const int* row = eidx;
  const int* col = eidx + NE;

  char* p = (char*)d_ws;
  auto alloc = [&](size_t b) {
    void* r = (void*)p;
    p += (b + 255) & ~(size_t)255;
    return r;
  };

  // Weight slices (pre-split, transposed to [n][k]):
  //  0: W0[0:128) (Pr)   1: W0[128:256) (Pc)  2: W0[256:384) (edge L1 A)
  //  3: W0[384:512) (Pu) 4: W1  5: W2
  //  6: W3[0:256) (node L1)  7: W3[256:384) (Pun)  8: W4  9: W5
  // 10: W6  11: W7  12: W8
  const int wk[13] = {128, 128, 128, 128, 256, 256, 256, 128, 256, 256, 384, 256, 256};
  const int wnn[13] = {256, 256, 256, 256, 256, 128, 256, 256, 256, 128, 256, 256, 128};
  const float* Wsrc[13] = {W[0],              W[0] + 128 * 256, W[0] + 256 * 256,
                           W[0] + 384 * 256,  W[1],             W[2],
                           W[3],              W[3] + 256 * 256, W[4],
                           W[5],              W[6],             W[7],
                           W[8]};
  bf16 *Wh[13], *Wl[13];
  for (int i = 0; i < 13; ++i) {
    Wh[i] = (bf16*)alloc((size_t)wk[i] * wnn[i] * 2);
    Wl[i] = (bf16*)alloc((size_t)wk[i] * wnn[i] * 2);
  }

  // Projection tables
  float* Pu = (float*)alloc((size_t)NG * 256 * 4);
  float* Pr = (float*)alloc((size_t)NN * 256 * 4);
  float* Pc = (float*)alloc((size_t)NN * 256 * 4);
  float* Pun = (float*)alloc((size_t)NG * 256 * 4);

  // CSR + aggregation buffers
  float* agg = (float*)alloc((size_t)NN * 128 * 4);
  int* eoff = (int*)alloc((size_t)(NN + 1) * 4);
  int* cursor = (int*)alloc((size_t)NN * 4);
  int* elist = (int*)alloc((size_t)NE * 4);
  float* eg_part = (float*)alloc((size_t)EGB * NG * 128 * 4);
  float* eg_final = (float*)alloc((size_t)NG * 128 * 4);

  char* zero_base = p;
  int* cnt_i = (int*)alloc((size_t)NN * 4);
  float* ngsum = (float*)alloc((size_t)64 * 128 * 128 * 4);
  float* cnt_gn = (float*)alloc(512);
  float* cnt_ge = (float*)alloc(512);
  float* zeros = (float*)alloc(256 * 4);
  size_t zero_len = (size_t)(p - zero_base);
  float* g_in = (float*)alloc((size_t)NG * 384 * 4);
  float* h_g0 = (float*)alloc((size_t)NG * 256 * 4);

  float* out_nodes = (float*)d_out;
  float* out_edges = out_nodes + (size_t)NN * 128;
  float* out_glob = out_nodes + (size_t)NN * 128 + (size_t)NE * 128;

  for (int i = 0; i < 13; ++i) {
    int tot = wk[i] * wnn[i];
    splitw_k<<<(tot + 255) / 256, 256, 0, stream>>>(Wsrc[i], Wh[i], Wl[i],
                                                    wk[i], wnn[i]);
  }
  hipMemsetAsync(zero_base, 0, zero_len, stream);

  const int gbN = (NN + 127) / 128;      // 235 (projection grid)
  const int gbE64 = (NE + 63) / 64;      // 4688 (fused edge grid)
  const int gbN64 = (NN + 63) / 64;      // 469  (fused node grid)

  // ---- CSR build over col ----
  csr_cnt_k<<<256, 256, 0, stream>>>(col, row, batch, cnt_i, cnt_ge);
  scan_k<<<1, SCAN_T, 0, stream>>>(cnt_i, eoff, cursor);
  csr_fill_k<<<(NE + 255) / 256, 256, 0, stream>>>(col, cursor, elist);

  // ---- Projections (K=128 each) ----
  gemm_wide<0><<<1, 512, 0, stream>>>(u, Wh[3], Wl[3], zeros, Pu, NG, 128, 0,
                                      nullptr, nullptr, nullptr, nullptr,
                                      nullptr, nullptr);
  gemm_wide<2><<<gbN, 512, 0, stream>>>(nullptr, Wh[0], Wl[0], zeros, Pr, NN,
                                        128, 0, nodes, nullptr, Pu, nullptr,
                                        nullptr, batch);
  gemm_wide<0><<<gbN, 512, 0, stream>>>(nodes, Wh[1], Wl[1], zeros, Pc, NN,
                                        128, 0, nullptr, nullptr, nullptr,
                                        nullptr, nullptr, nullptr);
  gemm_wide<0><<<1, 512, 0, stream>>>(u, Wh[7], Wl[7], zeros, Pun, NG, 128, 0,
                                      nullptr, nullptr, nullptr, nullptr,
                                      nullptr, nullptr);

  // ---- Edge MLP (fully fused) ----
  mlp_fused<1><<<gbE64, 256, 0, stream>>>(
      eattr, Wh[2], Wl[2], Bi[0], Wh[4], Wl[4], Bi[1], Wh[5], Wl[5], Bi[2],
      out_edges, NE, Pr, Pc, nullptr, row, col, nullptr);

  // ---- Aggregations ----
  gather_k<<<NN, 128, 0, stream>>>(out_edges, eoff, elist, agg);
  eg_hist_k<<<EGB, 256, 0, stream>>>(out_edges, row, batch, eg_part);
  eg_reduce_k<<<NG, 128, 0, stream>>>(eg_part, eg_final);

  // ---- Node MLP (fully fused) ----
  mlp_fused<2><<<gbN64, 256, 0, stream>>>(
      nullptr, Wh[6], Wl[6], Bi[3], Wh[8], Wl[8], Bi[4], Wh[9], Wl[9], Bi[5],
      out_nodes, NN, nodes, agg, Pun, nullptr, nullptr, batch);

  node_gagg_k<<<NN, 128, 0, stream>>>(out_nodes, batch, ngsum, cnt_gn);
  gin_k<<<NG, 128, 0, stream>>>(ngsum, eg_final, cnt_gn, cnt_ge, u, g_in);

  // ---- Global MLP ----
  gemm_wide<0><<<1, 512, 0, stream>>>(g_in, Wh[10], Wl[10], Bi[6], h_g0, NG,
                                      384, 1, nullptr, nullptr, nullptr,
                                      nullptr, nullptr, nullptr);
  gemm_wide<0><<<1, 512, 0, stream>>>(h_g0, Wh[11], Wl[11], Bi[7], h_g0, NG,
                                      256, 1, nullptr, nullptr, nullptr,
                                      nullptr, nullptr, nullptr);
  gemm128<<<dim3(1, 1), 256, 0, stream>>>(h_g0, Wh[12], Wl[12], Bi[8],
                                          out_glob, NG, 128, 256, 0);
}